// Round 5
// baseline (239.297 us; speedup 1.0000x reference)
//
#include <hip/hip_runtime.h>
#include <math.h>

#define N_NODES 50000
#define N_EDGES 800000
#define E_TOT   850000     // edges + self-loops
#define HEADS   8
#define HID     32
#define C1      256        // HEADS*HID
#define OUTC    16
#define NEG     0.2f
#define NB1     ((N_NODES + 255) / 256)   // scan blocks = 196 (<= 256 CUs -> co-resident)

__device__ __forceinline__ float lrelu(float v) { return v > 0.0f ? v : NEG * v; }

// ---- setup: pack xp = (x0,x1,x2,1) + CSR count/rank ----
__global__ __launch_bounds__(256) void k_setup(
    const float* __restrict__ x, const int* __restrict__ ei,
    float4* __restrict__ xp, int* __restrict__ cnt, int* __restrict__ rank)
{
    int e = blockIdx.x * 256 + threadIdx.x;
    if (e < N_NODES)
        xp[e] = make_float4(x[e * 3], x[e * 3 + 1], x[e * 3 + 2], 1.0f);
    if (e < E_TOT) {
        int d = (e < N_EDGES) ? ei[N_EDGES + e] : (e - N_EDGES);
        rank[e] = atomicAdd(&cnt[d], 1);
    }
}

// ---- single-kernel exclusive scan over cnt[0..N) -> off[0..N] ----
// 196 blocks, guaranteed co-resident (<=256 CUs); internal barrier via
// arrival counter sync[0] + release flag sync[1] (both re-zeroed by the
// memset before every launch).
__global__ __launch_bounds__(256) void k_scanAll(
    const int* __restrict__ cnt, int* __restrict__ off,
    int* __restrict__ bsum, int* __restrict__ bpre, int* __restrict__ syncw)
{
    __shared__ int s[256];
    __shared__ int sFlag;
    int tid = threadIdx.x, bid = blockIdx.x;
    int i = bid * 256 + tid;
    int v = (i < N_NODES) ? cnt[i] : 0;
    s[tid] = v;
    __syncthreads();
    for (int o = 1; o < 256; o <<= 1) {
        int t2 = (tid >= o) ? s[tid - o] : 0;
        __syncthreads();
        s[tid] += t2;
        __syncthreads();
    }
    int excl = s[tid] - v;
    int total = s[255];
    __syncthreads();
    if (tid == 0) {
        __hip_atomic_store(&bsum[bid], total, __ATOMIC_RELEASE, __HIP_MEMORY_SCOPE_AGENT);
        int prev = __hip_atomic_fetch_add(&syncw[0], 1, __ATOMIC_ACQ_REL, __HIP_MEMORY_SCOPE_AGENT);
        sFlag = (prev == NB1 - 1) ? 1 : 0;
    }
    __syncthreads();
    if (sFlag) {            // last-arriving block scans the 196 partials
        int bv = (tid < NB1) ? __hip_atomic_load(&bsum[tid], __ATOMIC_ACQUIRE, __HIP_MEMORY_SCOPE_AGENT) : 0;
        s[tid] = bv;
        __syncthreads();
        for (int o = 1; o < 256; o <<= 1) {
            int t2 = (tid >= o) ? s[tid - o] : 0;
            __syncthreads();
            s[tid] += t2;
            __syncthreads();
        }
        if (tid < NB1)
            __hip_atomic_store(&bpre[tid], s[tid] - bv, __ATOMIC_RELEASE, __HIP_MEMORY_SCOPE_AGENT);
        __syncthreads();
        if (tid == 0) {
            __threadfence();
            __hip_atomic_store(&syncw[1], 1, __ATOMIC_RELEASE, __HIP_MEMORY_SCOPE_AGENT);
        }
    }
    if (tid == 0) {
        while (__hip_atomic_load(&syncw[1], __ATOMIC_ACQUIRE, __HIP_MEMORY_SCOPE_AGENT) == 0)
            __builtin_amdgcn_s_sleep(16);
        sFlag = __hip_atomic_load(&bpre[bid], __ATOMIC_ACQUIRE, __HIP_MEMORY_SCOPE_AGENT);
    }
    __syncthreads();
    int base = sFlag;
    if (i < N_NODES) off[i] = base + excl;
    if (i == 0) off[N_NODES] = E_TOT;
}

// ---- fill: no atomics (rank precomputed) ----
__global__ void k_fill(const int* __restrict__ ei, const int* __restrict__ rank,
                       const int* __restrict__ off, int* __restrict__ csr_src)
{
    int e = blockIdx.x * blockDim.x + threadIdx.x;
    if (e >= E_TOT) return;
    int s, d;
    if (e < N_EDGES) { s = ei[e]; d = ei[N_EDGES + e]; } else { s = d = e - N_EDGES; }
    csr_src[off[d] + rank[e]] = s;
}

// ---- fused layer-1 aggregation + finalize + layer-2 transform ----
// block = 256 = 16 nodes x 16 lanes; lane = head(0..7) x sub(0..1).
// Stage A: softmax-weighted x-aggregation (xacc stays in LDS).
// Stage B: elu1 = ELU(xacc@W1/den + b1) into LDS + a_s2/a_d2 reduction.
// Stage C: h2 = elu1 @ W2.
__global__ __launch_bounds__(256) void k_aggfin(
    const int* __restrict__ off, const int* __restrict__ csr_src,
    const float4* __restrict__ xp,
    const float* __restrict__ W1,
    const float* __restrict__ att_s1, const float* __restrict__ att_d1,
    const float* __restrict__ b1, const float* __restrict__ W2,
    const float* __restrict__ att_s2, const float* __restrict__ att_d2,
    float* __restrict__ h2, float* __restrict__ a_s2, float* __restrict__ a_d2)
{
    __shared__ float  sW1[3 * C1];       // 3 KB
    __shared__ float  sAux[3 * C1];      // b1 | As2 | Ad2
    __shared__ float  sW2t[OUTC][272];   // transposed W2, stride 272 (2-way banks = free)
    __shared__ float  sElu[16][272];
    __shared__ float  sAtt[48];          // As1[24] | Ad1[24], layout [k*8+h]
    __shared__ float4 sXac[16][8];       // per-(node,head) (x0,x1,x2,den)
    int t = threadIdx.x;
    for (int i = t; i < 3 * C1; i += 256) sW1[i] = W1[i];
    sAux[t] = b1[t];
    {   // fold As2[k]/Ad2[k] = sum_j W2[k,j]*att2[j]
        float as2 = 0.0f, ad2 = 0.0f;
        for (int j = 0; j < OUTC; j++) {
            float w = W2[t * OUTC + j];
            as2 = fmaf(w, att_s2[j], as2);
            ad2 = fmaf(w, att_d2[j], ad2);
        }
        sAux[C1 + t] = as2; sAux[2 * C1 + t] = ad2;
    }
    for (int i = t; i < C1 * OUTC; i += 256) {
        int k = i >> 4, j = i & 15;
        sW2t[j][k] = W2[i];
    }
    if (t < 48) {   // fold As1/Ad1: [k,h] = sum_c W1[k,h*32+c]*att1[h,c]
        int q = t & 7, k = (t >> 3) % 3;
        bool isD = t >= 24;
        const float* att = isD ? att_d1 : att_s1;
        float a = 0.0f;
        for (int c = 0; c < HID; c++)
            a = fmaf(W1[k * C1 + q * HID + c], att[q * HID + c], a);
        sAtt[(isD ? 24 : 0) + k * 8 + q] = a;
    }
    __syncthreads();

    int n = t >> 4, l = t & 15;
    int h = l & 7, sub = l >> 3;
    int node = blockIdx.x * 16 + n;      // N = 3125*16 exact
    float s0 = sAtt[h],      s1 = sAtt[8 + h],  s2 = sAtt[16 + h];
    float d0 = sAtt[24 + h], d1 = sAtt[32 + h], d2 = sAtt[40 + h];
    float4 xd = xp[node];
    float ad = xd.x * d0 + xd.y * d1 + xd.z * d2;
    int beg = off[node], end = off[node + 1];
    float a0 = 0.0f, a1 = 0.0f, a2 = 0.0f, a3 = 0.0f;
    int nfull = beg + ((end - beg) & ~15);
    for (int base = beg; base < nfull; base += 16) {
        int sm = csr_src[base + l];
        float4 xv = xp[sm];
        #pragma unroll
        for (int j = 0; j < 8; j++) {
            int jj = sub * 8 + j;
            float vx = __shfl(xv.x, jj, 16);
            float vy = __shfl(xv.y, jj, 16);
            float vz = __shfl(xv.z, jj, 16);
            float as = vx * s0 + vy * s1 + vz * s2;
            float p = __expf(lrelu(as + ad));
            a0 = fmaf(p, vx, a0);
            a1 = fmaf(p, vy, a1);
            a2 = fmaf(p, vz, a2);
            a3 += p;
        }
    }
    int m = end - nfull;                 // 0..15 tail
    if (m > 0) {
        int sm = csr_src[(l < m) ? (nfull + l) : nfull];
        float4 xv = xp[sm];
        int jbeg = sub * 8, jlim = min(jbeg + 8, m);
        for (int j = jbeg; j < jlim; j++) {
            float vx = __shfl(xv.x, j, 16);
            float vy = __shfl(xv.y, j, 16);
            float vz = __shfl(xv.z, j, 16);
            float as = vx * s0 + vy * s1 + vz * s2;
            float p = __expf(lrelu(as + ad));
            a0 = fmaf(p, vx, a0);
            a1 = fmaf(p, vy, a1);
            a2 = fmaf(p, vz, a2);
            a3 += p;
        }
    }
    a0 += __shfl_xor(a0, 8, 16);
    a1 += __shfl_xor(a1, 8, 16);
    a2 += __shfl_xor(a2, 8, 16);
    a3 += __shfl_xor(a3, 8, 16);
    if (sub == 0) sXac[n][h] = make_float4(a0, a1, a2, a3);
    __syncthreads();

    // Stage B
    float as2v = 0.0f, ad2v = 0.0f;
    for (int i = 0; i < 16; i++) {
        int c = l + 16 * i;
        int hh = c >> 5;
        float4 xa = sXac[n][hh];
        float z = (xa.x * sW1[c] + xa.y * sW1[C1 + c] + xa.z * sW1[2 * C1 + c])
                  / (xa.w + 1e-16f) + sAux[c];
        float e = z > 0.0f ? z : expm1f(z);
        sElu[n][c] = e;
        as2v = fmaf(e, sAux[C1 + c], as2v);
        ad2v = fmaf(e, sAux[2 * C1 + c], ad2v);
    }
    for (int o = 1; o < 16; o <<= 1) {
        as2v += __shfl_xor(as2v, o, 16);
        ad2v += __shfl_xor(ad2v, o, 16);
    }
    if (l == 0) { a_s2[node] = as2v; a_d2[node] = ad2v; }
    __syncthreads();

    // Stage C
    const float4* e4 = (const float4*)&sElu[n][0];
    const float4* w4 = (const float4*)&sW2t[l][0];
    float acc = 0.0f;
    #pragma unroll 8
    for (int k = 0; k < 64; k++) {
        float4 a = e4[k], b = w4[k];
        acc = fmaf(a.x, b.x, fmaf(a.y, b.y, fmaf(a.z, b.z, fmaf(a.w, b.w, acc))));
    }
    h2[node * OUTC + l] = acc;
}

// ---- layer-2 aggregation: 16 lanes per dst (lane = channel) ----
__global__ __launch_bounds__(256) void k_agg2(
    const int* __restrict__ off, const int* __restrict__ csr_src,
    const float* __restrict__ a_s, const float* __restrict__ a_d,
    const float* __restrict__ h2, const float* __restrict__ bias,
    float* __restrict__ out)
{
    int tid = threadIdx.x;
    int c = tid & 15;
    int dst = blockIdx.x * 16 + (tid >> 4);
    if (dst >= N_NODES) return;
    int beg = off[dst], end = off[dst + 1];
    float ad = a_d[dst];
    float acc = 0.0f, denp = 0.0f;
    int nfull = beg + ((end - beg) & ~15);
    for (int base = beg; base < nfull; base += 16) {
        int sm = csr_src[base + c];
        float p = __expf(lrelu(a_s[sm] + ad));
        denp += p;
        #pragma unroll
        for (int j = 0; j < 16; j++) {
            int s = __shfl(sm, j, 16);
            float pj = __shfl(p, j, 16);
            acc = fmaf(pj, h2[s * OUTC + c], acc);
        }
    }
    if (nfull < end) {
        int idx = nfull + c;
        int sm = 0; float p = 0.0f;
        if (idx < end) { sm = csr_src[idx]; p = __expf(lrelu(a_s[sm] + ad)); }
        denp += p;
        int mm = end - nfull;
        for (int j = 0; j < mm; j++) {
            int s = __shfl(sm, j, 16);
            float pj = __shfl(p, j, 16);
            acc = fmaf(pj, h2[s * OUTC + c], acc);
        }
    }
    for (int o = 1; o < 16; o <<= 1) denp += __shfl_xor(denp, o, 16);
    out[dst * OUTC + c] = acc / (denp + 1e-16f) + bias[c];
}

extern "C" void kernel_launch(void* const* d_in, const int* in_sizes, int n_in,
                              void* d_out, int out_size, void* d_ws, size_t ws_size,
                              hipStream_t stream)
{
    (void)in_sizes; (void)n_in; (void)out_size; (void)ws_size;
    const float* x    = (const float*)d_in[0];
    const int*   ei   = (const int*)d_in[1];
    const float* W1   = (const float*)d_in[2];
    const float* as1w = (const float*)d_in[3];
    const float* ad1w = (const float*)d_in[4];
    const float* b1   = (const float*)d_in[5];
    const float* W2   = (const float*)d_in[6];
    const float* as2w = (const float*)d_in[7];
    const float* ad2w = (const float*)d_in[8];
    const float* b2   = (const float*)d_in[9];
    float* out = (float*)d_out;

    const long N = N_NODES;
    char* p = (char*)d_ws;
    auto alloc = [&](size_t elems) {          // 16B-aligned
        void* r = p; p += ((elems + 3) & ~(size_t)3) * 4; return r;
    };

    float4* xp      = (float4*)alloc(N * 4);
    int*   cnt      = (int*)alloc(N + 8);     // cnt[N] + syncw[2] contiguous
    int*   syncw    = cnt + N;
    int*   bsum     = (int*)alloc(256);
    int*   bpre     = (int*)alloc(256);
    int*   off      = (int*)alloc(N + 1);
    int*   rank     = (int*)alloc(E_TOT);
    int*   csr_src  = (int*)alloc(E_TOT);
    float* h2v      = (float*)alloc(N * OUTC);
    float* a_s2     = (float*)alloc(N);
    float* a_d2     = (float*)alloc(N);

    hipMemsetAsync(cnt, 0, (size_t)(N + 2) * sizeof(int), stream);

    k_setup<<<(E_TOT + 255) / 256, 256, 0, stream>>>(x, ei, xp, cnt, rank);
    k_scanAll<<<NB1, 256, 0, stream>>>(cnt, off, bsum, bpre, syncw);
    k_fill<<<(E_TOT + 255) / 256, 256, 0, stream>>>(ei, rank, off, csr_src);
    k_aggfin<<<(int)(N / 16), 256, 0, stream>>>(
        off, csr_src, xp, W1, as1w, ad1w, b1, W2, as2w, ad2w, h2v, a_s2, a_d2);
    k_agg2<<<(int)(N / 16), 256, 0, stream>>>(off, csr_src, a_s2, a_d2, h2v, b2, out);
}